// Round 11
// baseline (155.390 us; speedup 1.0000x reference)
//
#include <hip/hip_runtime.h>
#include <stdint.h>

#define IN_F  4096
#define OUT_F 4096
#define BW    512
#define WB2   1280   // padded k-window per 256-col tile: [bcol-512, bcol+768)
#define BM    256
#define BN    256

typedef __bf16 bf16x8 __attribute__((ext_vector_type(8)));
typedef float  f32x4  __attribute__((ext_vector_type(4)));

__device__ __forceinline__ int band_start(int o) {
    if (o <= 512)  return o * 513 + ((o * (o - 1)) >> 1);
    if (o <= 3584) return 393472 + (o - 512) * 1025;
    const int d = o - 3584;
    return 3542272 + (((1024 + 4609 - o) * d) >> 1);
}

__device__ __forceinline__ uint16_t f32_to_bf16(float f) {
    uint32_t u = __builtin_bit_cast(uint32_t, f);
    u += 0x7FFFu + ((u >> 16) & 1u);   // RNE
    return (uint16_t)(u >> 16);
}

// ---- pass 1: densify band -> wd[o][j], j indexes k = (o&~255)-512+j, zero outside band
__global__ __launch_bounds__(256) void cvt_w(const float* __restrict__ wv,
                                             uint16_t* __restrict__ wd) {
    const int o = blockIdx.y;
    const int j = blockIdx.x * 256 + threadIdx.x;     // 0..1279
    const int i = (o & ~(BM - 1)) - BW + j;
    uint16_t v = 0;
    if (i >= o - BW && i <= o + BW && i >= 0 && i < IN_F) {
        const int lo = (o > BW) ? (o - BW) : 0;
        v = f32_to_bf16(wv[band_start(o) + (i - lo)]);
    }
    wd[o * WB2 + j] = v;
}

// ---- pass 2: 256x256, BK=64, dbuf-2. A: fused f32->bf16 reg-staging (T14 split:
// issue q0, cvt+ds_write q2/q3) -> cvt_x dispatch eliminated. B: global_load_lds.
// Boundary per tile: vmcnt(0)+lgkmcnt(0)+barrier. No setprio. Persistent 2 row-jobs.
__global__ __launch_bounds__(512, 1) void band_gemm_v11(
    const float* __restrict__ xf,
    const uint16_t* __restrict__ wd,
    const float* __restrict__ bias,
    float* __restrict__ out)
{
    __shared__ __align__(128) uint8_t lds[131072];   // 2 bufs x {A 32K, B 32K}

    // bx-grouped XCD mapping on 256 blocks: XCD x owns column panels {2x, 2x+1}
    const int id  = blockIdx.x;
    const int bx  = 2 * (id & 7) + ((id >> 3) & 1);
    const int byg = id >> 4;                 // rows byg and byg+16
    const int bcol = bx * BN;
    const int brow0 = byg * BM;

    const int wlo    = bcol - BW;
    const int kstart = wlo > 0 ? wlo : 0;
    const int kend   = (bcol + BN + BW) < IN_F ? (bcol + BN + BW) : IN_F;
    const int nt     = (kend - kstart) >> 6;      // 12/16/20 K64 tiles
    const int j0     = kstart - wlo;

    const int tid  = threadIdx.x;
    const int w    = tid >> 6;
    const int lane = tid & 63;
    const int ln   = lane & 15;
    const int kc   = lane >> 4;
    const int wm   = w >> 2;            // 0..1  (M half, 128 rows)
    const int wn   = w & 3;             // 0..3  (N quarter, 64 cols)

    // staging geometry: region = 64 rows x 128 B (8 KB); thread covers bytes tid*16.
    // LDS(row, c) stores global chunk c ^ (row&7)  [chunk = 16 B] -> proven layout.
    const int srow = tid >> 3;          // 0..63
    const int csrc = (tid & 7) ^ (srow & 7);
    const float*    aF0  = xf + (size_t)(brow0 + srow) * IN_F + kstart + csrc * 8;
    const float*    aF1  = aF0 + (size_t)16 * BM * IN_F;          // +4096 rows
    const uint16_t* bSrc = wd + (size_t)(bcol + srow) * WB2 + j0 + csrc * 8;

#define GLOAD(srcp, dst_off)                                                             \
    __builtin_amdgcn_global_load_lds(                                                    \
        (const __attribute__((address_space(1))) uint32_t*)(srcp),                       \
        (__attribute__((address_space(3))) uint32_t*)(lds + (dst_off) + (w << 10)),      \
        16, 0, 0)

    // B half h (rows h*128..h*128+127) of tile tv -> 2 gloads into buf base bb
#define STG_B(tv_, h_, bb_) { const uint16_t* p_ = bSrc + (size_t)((h_) * 128) * WB2 + (tv_) * 64; \
        GLOAD(p_, (bb_) + 32768 + (h_) * 16384);                                         \
        GLOAD(p_ + (size_t)64 * WB2, (bb_) + 32768 + (h_) * 16384 + 8192); }

    // A fused staging: issue 8 float4 f32 loads for tile tv (regions r=0..3, 32B each)
    float4 rA[4][2];
#define A_ISSUE(AF, tv_) {                                                               \
    _Pragma("unroll")                                                                    \
    for (int r_ = 0; r_ < 4; ++r_) {                                                     \
        const float* p_ = (AF) + (size_t)(r_ * 64) * IN_F + (tv_) * 64;                  \
        rA[r_][0] = *(const float4*)p_;                                                  \
        rA[r_][1] = *(const float4*)(p_ + 4);                                            \
    } }
    // cvt + ds_write regions {2*pair, 2*pair+1} into buf base bb (RNE via HW cvt_pk)
#define A_WRITE(pair_, bb_) {                                                            \
    _Pragma("unroll")                                                                    \
    for (int r_ = 0; r_ < 2; ++r_) {                                                     \
        const int rr_ = (pair_) * 2 + r_;                                                \
        uint32_t d0_, d1_, d2_, d3_;                                                     \
        asm("v_cvt_pk_bf16_f32 %0, %1, %2" : "=v"(d0_) : "v"(rA[rr_][0].x), "v"(rA[rr_][0].y)); \
        asm("v_cvt_pk_bf16_f32 %0, %1, %2" : "=v"(d1_) : "v"(rA[rr_][0].z), "v"(rA[rr_][0].w)); \
        asm("v_cvt_pk_bf16_f32 %0, %1, %2" : "=v"(d2_) : "v"(rA[rr_][1].x), "v"(rA[rr_][1].y)); \
        asm("v_cvt_pk_bf16_f32 %0, %1, %2" : "=v"(d3_) : "v"(rA[rr_][1].z), "v"(rA[rr_][1].w)); \
        *(uint4*)(lds + (bb_) + rr_ * 8192 + tid * 16) = make_uint4(d0_, d1_, d2_, d3_); \
    } }

    // fragment addressing (proven zero-conflict swizzle); k-step 1 = byte ^ 64
    const int cswz = (kc ^ (ln & 7)) << 4;
    int aOff[8], bOff[4];
    #pragma unroll
    for (int a = 0; a < 8; ++a) aOff[a] = ((wm * 128 + a * 16 + ln) << 7) + cswz;
    #pragma unroll
    for (int n = 0; n < 4; ++n) bOff[n] = 32768 + ((wn * 64 + n * 16 + ln) << 7) + cswz;

    bf16x8 am[4][2], bn0[2][2], bn1[2][2];
#define LD_A(BB, MQ) {                                                                   \
    _Pragma("unroll")                                                                    \
    for (int s_ = 0; s_ < 4; ++s_) {                                                     \
        am[s_][0] = *(const bf16x8*)(lds + (BB) + aOff[(MQ) * 4 + s_]);                  \
        am[s_][1] = *(const bf16x8*)(lds + (BB) + (aOff[(MQ) * 4 + s_] ^ 64));           \
    } }
#define LD_B(DST, BB, NQ) {                                                              \
    _Pragma("unroll")                                                                    \
    for (int s_ = 0; s_ < 2; ++s_) {                                                     \
        DST[s_][0] = *(const bf16x8*)(lds + (BB) + bOff[(NQ) * 2 + s_]);                 \
        DST[s_][1] = *(const bf16x8*)(lds + (BB) + (bOff[(NQ) * 2 + s_] ^ 64));          \
    } }
#define MFMAPH(MROW, NCOL, BB) {                                                         \
    _Pragma("unroll")                                                                    \
    for (int a_ = 0; a_ < 4; ++a_) {                                                     \
        _Pragma("unroll")                                                                \
        for (int n_ = 0; n_ < 2; ++n_) {                                                 \
            acc[(MROW) + a_][(NCOL) + n_] = __builtin_amdgcn_mfma_f32_16x16x32_bf16(     \
                am[a_][0], BB[n_][0], acc[(MROW) + a_][(NCOL) + n_], 0, 0, 0);           \
            acc[(MROW) + a_][(NCOL) + n_] = __builtin_amdgcn_mfma_f32_16x16x32_bf16(     \
                am[a_][1], BB[n_][1], acc[(MROW) + a_][(NCOL) + n_], 0, 0, 0);           \
        } } }

#define BOUNDARY  asm volatile("s_waitcnt vmcnt(0)" ::: "memory");                       \
                  asm volatile("s_waitcnt lgkmcnt(0)" ::: "memory");                     \
                  __builtin_amdgcn_s_barrier();                                          \
                  asm volatile("" ::: "memory")

#define PRO(AF) {                                                                        \
    A_ISSUE(AF, 0);                                                                      \
    STG_B(0, 0, 0); STG_B(0, 1, 0);                                                      \
    A_WRITE(0, 0); A_WRITE(1, 0);                                                        \
    BOUNDARY; }

#define KLOOP(AF) {                                                                      \
    for (int v = 0; v < nt; ++v) {                                                       \
        const int cur = (v & 1) << 16;                                                   \
        const int nxt = cur ^ 65536;                                                     \
        const bool st = (v + 1 < nt);                                                    \
        /* q0 */                                                                         \
        LD_A(cur, 0); LD_B(bn0, cur, 0);                                                 \
        if (st) A_ISSUE(AF, v + 1);                                                      \
        MFMAPH(0, 0, bn0);                                                               \
        /* q1 */                                                                         \
        LD_B(bn1, cur, 1);                                                               \
        if (st) STG_B(v + 1, 0, nxt);                                                    \
        MFMAPH(0, 2, bn1);                                                               \
        /* q2 */                                                                         \
        LD_A(cur, 1);                                                                    \
        if (st) A_WRITE(0, nxt);                                                         \
        MFMAPH(4, 2, bn1);                                                               \
        /* q3 */                                                                         \
        if (st) { STG_B(v + 1, 1, nxt); A_WRITE(1, nxt); }                               \
        MFMAPH(4, 0, bn0);                                                               \
        BOUNDARY;                                                                        \
    } }

    // epilogue: C/D map col = lane&15, row = (lane>>4)*4 + q  (verified R2-R10)
#define EPI(BROWX) {                                                                     \
    _Pragma("unroll")                                                                    \
    for (int a_ = 0; a_ < 8; ++a_) {                                                     \
        _Pragma("unroll")                                                                \
        for (int q_ = 0; q_ < 4; ++q_) {                                                 \
            const int row_ = (BROWX) + wm * 128 + a_ * 16 + (kc << 2) + q_;              \
            float* po_ = out + (size_t)row_ * OUT_F + ocol;                              \
            _Pragma("unroll")                                                            \
            for (int n_ = 0; n_ < 4; ++n_)                                               \
                po_[n_ * 16] = acc[a_][n_][q_] + bsv[n_];                                 \
        } } }

    const int ocol = bcol + wn * 64 + ln;
    float bsv[4];
    #pragma unroll
    for (int n = 0; n < 4; ++n) bsv[n] = bias[ocol + n * 16];

    f32x4 acc[8][4] = {};

    // ---- row-tile g=0
    PRO(aF0);
    KLOOP(aF0);
    // ---- g=1 prologue first (stages under epilogue-0 stores), then epilogue g0
    PRO(aF1);
    EPI(brow0);
    #pragma unroll
    for (int a = 0; a < 8; ++a)
        #pragma unroll
        for (int n = 0; n < 4; ++n) acc[a][n] = (f32x4){0.f, 0.f, 0.f, 0.f};
    KLOOP(aF1);
    EPI(brow0 + 16 * BM);

#undef GLOAD
#undef STG_B
#undef A_ISSUE
#undef A_WRITE
#undef LD_A
#undef LD_B
#undef MFMAPH
#undef BOUNDARY
#undef PRO
#undef KLOOP
#undef EPI
}

// ---- fallback (odd M / small ws): fp32 tiled kernel, known correct
__global__ __launch_bounds__(256) void band_gemm_f32(
    const float* __restrict__ x, const float* __restrict__ wv,
    const float* __restrict__ bias, float* __restrict__ out, int M)
{
    __shared__ float Xs[128][33];
    __shared__ float Ws[32][130];
    const int tid = threadIdx.x;
    const int tx = tid & 15, ty = tid >> 4;
    const int bcol = blockIdx.x * 128, brow = blockIdx.y * 128;
    const int klo = (bcol >= BW) ? (bcol - BW) : 0;
    const int khi = min(IN_F, bcol + 128 + BW);
    float acc[8][8];
    #pragma unroll
    for (int a = 0; a < 8; ++a)
        #pragma unroll
        for (int b = 0; b < 8; ++b) acc[a][b] = 0.f;
    const int xc4 = (tid & 7) * 4, xr0 = tid >> 3;
    const int wc = tid & 31, wr0 = tid >> 5;
    for (int k0 = klo; k0 < khi; k0 += 32) {
        #pragma unroll
        for (int p = 0; p < 4; ++p) {
            const int rr = xr0 + 32 * p;
            const float4 v = *reinterpret_cast<const float4*>(&x[(size_t)(brow + rr) * IN_F + (k0 + xc4)]);
            Xs[rr][xc4 + 0] = v.x; Xs[rr][xc4 + 1] = v.y; Xs[rr][xc4 + 2] = v.z; Xs[rr][xc4 + 3] = v.w;
        }
        const int i = k0 + wc;
        #pragma unroll
        for (int p = 0; p < 16; ++p) {
            const int rr = wr0 + 8 * p;
            const int o = bcol + rr;
            const int lo = (o >= BW) ? (o - BW) : 0;
            float v = 0.f;
            if (i >= o - BW && i <= o + BW) v = wv[band_start(o) + (i - lo)];
            Ws[wc][rr] = v;
        }
        __syncthreads();
        #pragma unroll
        for (int k = 0; k < 32; ++k) {
            float amv[8];
            #pragma unroll
            for (int a = 0; a < 8; ++a) amv[a] = Xs[ty * 8 + a][k];
            float bo[8];
            #pragma unroll
            for (int b = 0; b < 4; ++b) { bo[b] = Ws[k][tx * 4 + b]; bo[4 + b] = Ws[k][tx * 4 + 64 + b]; }
            #pragma unroll
            for (int a = 0; a < 8; ++a)
                #pragma unroll
                for (int b = 0; b < 8; ++b) acc[a][b] = fmaf(amv[a], bo[b], acc[a][b]);
        }
        __syncthreads();
    }
    #pragma unroll
    for (int a = 0; a < 8; ++a) {
        const size_t row = (size_t)(brow + ty * 8 + a);
        #pragma unroll
        for (int b = 0; b < 4; ++b) {
            out[row * OUT_F + bcol + tx * 4 + b]      = acc[a][b]     + bias[bcol + tx * 4 + b];
            out[row * OUT_F + bcol + tx * 4 + 64 + b] = acc[a][4 + b] + bias[bcol + tx * 4 + 64 + b];
        }
    }
}

extern "C" void kernel_launch(void* const* d_in, const int* in_sizes, int n_in,
                              void* d_out, int out_size, void* d_ws, size_t ws_size,
                              hipStream_t stream) {
    const float* x    = (const float*)d_in[0];
    const float* wv   = (const float*)d_in[1];
    const float* bias = (const float*)d_in[2];
    float* out        = (float*)d_out;

    const int M = in_sizes[0] / IN_F;                         // 8192
    const size_t wd_bytes = (size_t)OUT_F * WB2 * 2;          // 10.5 MB

    if (ws_size >= wd_bytes && M == 8192) {
        uint16_t* wdp = (uint16_t*)d_ws;
        cvt_w<<<dim3(WB2 / 256, OUT_F), 256, 0, stream>>>(wv, wdp);
        band_gemm_v11<<<256, 512, 0, stream>>>(x, wdp, bias, out);
    } else {
        dim3 grid(OUT_F / 128, M / 128);
        band_gemm_f32<<<grid, 256, 0, stream>>>(x, wv, bias, out, M);
    }
}

// Round 12
// 146.602 us; speedup vs baseline: 1.0599x; 1.0599x over previous
//
#include <hip/hip_runtime.h>
#include <stdint.h>

#define IN_F  4096
#define OUT_F 4096
#define BW    512
#define WB2   1280   // padded k-window per 256-col tile: [bcol-512, bcol+768)
#define BM    256
#define BN    256

typedef __bf16 bf16x8 __attribute__((ext_vector_type(8)));
typedef float  f32x16 __attribute__((ext_vector_type(16)));

__device__ __forceinline__ int band_start(int o) {
    if (o <= 512)  return o * 513 + ((o * (o - 1)) >> 1);
    if (o <= 3584) return 393472 + (o - 512) * 1025;
    const int d = o - 3584;
    return 3542272 + (((1024 + 4609 - o) * d) >> 1);
}

__device__ __forceinline__ uint16_t f32_to_bf16(float f) {
    uint32_t u = __builtin_bit_cast(uint32_t, f);
    u += 0x7FFFu + ((u >> 16) & 1u);   // RNE
    return (uint16_t)(u >> 16);
}

// ---- pass 1: x fp32 -> bf16 dense [M][4096]
__global__ __launch_bounds__(256) void cvt_x(const float* __restrict__ x,
                                             uint16_t* __restrict__ xb, int n4) {
    const int stride = gridDim.x * 256;
    for (int i = blockIdx.x * 256 + threadIdx.x; i < n4; i += stride) {
        const float4 v = reinterpret_cast<const float4*>(x)[i];
        const uint32_t lo = (uint32_t)f32_to_bf16(v.x) | ((uint32_t)f32_to_bf16(v.y) << 16);
        const uint32_t hi = (uint32_t)f32_to_bf16(v.z) | ((uint32_t)f32_to_bf16(v.w) << 16);
        reinterpret_cast<uint2*>(xb)[i] = make_uint2(lo, hi);
    }
}

// ---- pass 2: densify band -> wd[o][j], j indexes k = (o&~255)-512+j, zero outside band
__global__ __launch_bounds__(256) void cvt_w(const float* __restrict__ wv,
                                             uint16_t* __restrict__ wd) {
    const int o = blockIdx.y;
    const int j = blockIdx.x * 256 + threadIdx.x;     // 0..1279
    const int i = (o & ~(BM - 1)) - BW + j;
    uint16_t v = 0;
    if (i >= o - BW && i <= o + BW && i >= 0 && i < IN_F) {
        const int lo = (o > BW) ? (o - BW) : 0;
        v = f32_to_bf16(wv[band_start(o) + (i - lo)]);
    }
    wd[o * WB2 + j] = v;
}

// ---- pass 3: v10 structure (ring-9, counted vmcnt(2), 1 barrier/tile, no setprio,
// persistent 2 row-jobs) with MFMA 32x32x16 (half the MFMA count, 15% faster pipe).
__global__ __launch_bounds__(512, 1) void band_gemm_v12(
    const uint16_t* __restrict__ xb,
    const uint16_t* __restrict__ wd,
    const float* __restrict__ bias,
    float* __restrict__ out)
{
    __shared__ __align__(128) uint8_t lds[9 * 16384];   // 144 KB, 9 unit slots

    // bx-grouped XCD mapping on 256 blocks: XCD x owns column panels {2x, 2x+1}
    const int id  = blockIdx.x;
    const int bx  = 2 * (id & 7) + ((id >> 3) & 1);
    const int byg = id >> 4;                 // rows byg and byg+16
    const int bcol = bx * BN;
    const int brow0 = byg * BM;

    const int wlo    = bcol - BW;
    const int kstart = wlo > 0 ? wlo : 0;
    const int kend   = (bcol + BN + BW) < IN_F ? (bcol + BN + BW) : IN_F;
    const int nt     = (kend - kstart) >> 6;      // 12/16/20 K64 tiles
    const int j0     = kstart - wlo;

    const int tid  = threadIdx.x;
    const int w    = tid >> 6;
    const int lane = tid & 63;
    const int l31  = lane & 31;
    const int kc32 = lane >> 5;        // 0..1
    const int wm   = w >> 2;            // 0..1  (M half, 128 rows)
    const int wn   = w & 3;             // 0..3  (N quarter, 64 cols)

    // staging: unit = 128 rows x 128 B (16 KB = 2 gloads of 64 rows each)
    // LDS(row,c) holds global chunk c ^ (row&7)  [chunk = 16 B] -> pre-swizzled src
    const int srow = tid >> 3;          // 0..63
    const int csrc = (tid & 7) ^ (srow & 7);
    const uint16_t* aSrc0 = xb + (size_t)(brow0 + srow) * IN_F + kstart + csrc * 8;
    const uint16_t* aSrc1 = aSrc0 + (size_t)16 * BM * IN_F;      // rows +4096
    const uint16_t* bSrc  = wd + (size_t)(bcol + srow) * WB2 + j0 + csrc * 8;

#define GLOAD(srcp, dst_off)                                                             \
    __builtin_amdgcn_global_load_lds(                                                    \
        (const __attribute__((address_space(1))) uint32_t*)(srcp),                       \
        (__attribute__((address_space(3))) uint32_t*)(lds + (dst_off) + (w << 10)),      \
        16, 0, 0)

    // unit j of tile w_: j=0 A rows 0-127, j=1 B rows 0-127, j=2 A rows 128-255, j=3 B rows 128-255
#define STG_UNIT(AS, w_, j_, slot_) {                                                    \
        if (((j_) & 1) == 0) {                                                           \
            const uint16_t* p_ = (AS) + (size_t)(((j_) >> 1) * 128) * IN_F + (w_) * 64;  \
            GLOAD(p_, (slot_) << 14);                                                    \
            GLOAD(p_ + (size_t)64 * IN_F, ((slot_) << 14) + 8192);                       \
        } else {                                                                         \
            const uint16_t* p_ = bSrc + (size_t)(((j_) >> 1) * 128) * WB2 + (w_) * 64;   \
            GLOAD(p_, (slot_) << 14);                                                    \
            GLOAD(p_ + (size_t)64 * WB2, ((slot_) << 14) + 8192);                        \
        } }

    // 32x32x16 fragment addressing: lane reads row (l&31) of its 32-row block,
    // 8 contiguous k at k-chunk (s*2 + (lane>>5)); swizzle chunk ^ (row&7).
    // Quarter-wave bank check: 16 rows x same chunk -> 8 swz-chunks x 2 = 2-way = free.
#define LD_A32(BASE, PAIR) {                                                             \
    _Pragma("unroll")                                                                    \
    for (int p_ = 0; p_ < 2; ++p_) {                                                     \
        const int row_ = (PAIR) * 64 + p_ * 32 + l31;                                    \
        _Pragma("unroll")                                                                \
        for (int s_ = 0; s_ < 4; ++s_)                                                   \
            am32[p_][s_] = *(const bf16x8*)(lds + (BASE) + (row_ << 7)                   \
                              + (((s_ * 2 + kc32) ^ (row_ & 7)) << 4));                  \
    } }
#define LD_B32(DST, BASE, NF) {                                                          \
        const int row_ = (wn & 1) * 64 + (NF) * 32 + l31;                                \
        _Pragma("unroll")                                                                \
        for (int s_ = 0; s_ < 4; ++s_)                                                   \
            DST[s_] = *(const bf16x8*)(lds + (BASE) + (row_ << 7)                        \
                              + (((s_ * 2 + kc32) ^ (row_ & 7)) << 4));                  \
    }
#define MFMAPH32(PAIR, NF, BB) {                                                         \
    _Pragma("unroll")                                                                    \
    for (int s_ = 0; s_ < 4; ++s_) {                                                     \
        _Pragma("unroll")                                                                \
        for (int p_ = 0; p_ < 2; ++p_)                                                   \
            acc[(PAIR) * 2 + p_][NF] = __builtin_amdgcn_mfma_f32_32x32x16_bf16(          \
                am32[p_][s_], BB[s_], acc[(PAIR) * 2 + p_][NF], 0, 0, 0);                \
    } }

    f32x16 acc[4][2] = {};
    bf16x8 am32[2][4], bn0[4], bn1[4];

#define PRO(AS) {                                                                        \
    STG_UNIT(AS, 0, 0, 0); STG_UNIT(AS, 0, 1, 1); STG_UNIT(AS, 0, 2, 2);                 \
    STG_UNIT(AS, 0, 3, 3); STG_UNIT(AS, 1, 0, 4); }

#define KLOOP(AS) {                                                                      \
    int s4v = 0;                                                                         \
    for (int v = 0; v < nt; ++v) {                                                       \
        int sA = s4v + (wm << 1);            if (sA >= 9) sA -= 9;                       \
        int sB = s4v + 1 + ((wn >> 1) << 1); if (sB >= 9) sB -= 9;                       \
        const int aBase = sA << 14, bBase = sB << 14;                                    \
        int st0 = s4v + 5; if (st0 >= 9) st0 -= 9;                                       \
        int st1 = st0 + 1; if (st1 >= 9) st1 -= 9;                                       \
        int st2 = st1 + 1; if (st2 >= 9) st2 -= 9;                                       \
        int st3 = st2 + 1; if (st3 >= 9) st3 -= 9;                                       \
        const bool stg_q012 = (v + 1 < nt);                                              \
        const bool stg_q3   = (v + 2 < nt);                                              \
        /* q0: pair0 x nf0 */                                                            \
        LD_A32(aBase, 0);                                                                \
        LD_B32(bn0, bBase, 0);                                                           \
        if (stg_q012) STG_UNIT(AS, v + 1, 1, st0);                                       \
        MFMAPH32(0, 0, bn0);                                                             \
        /* q1: pair0 x nf1 */                                                            \
        LD_B32(bn1, bBase, 1);                                                           \
        if (stg_q012) STG_UNIT(AS, v + 1, 2, st1);                                       \
        MFMAPH32(0, 1, bn1);                                                             \
        /* q2: pair1 x nf1 */                                                            \
        LD_A32(aBase, 1);                                                                \
        if (stg_q012) STG_UNIT(AS, v + 1, 3, st2);                                       \
        MFMAPH32(1, 1, bn1);                                                             \
        /* q3: pair1 x nf0 */                                                            \
        if (stg_q3) STG_UNIT(AS, v + 2, 0, st3);                                         \
        MFMAPH32(1, 0, bn0);                                                             \
        if (v + 1 < nt) {                                                                \
            if (v + 2 < nt) { asm volatile("s_waitcnt vmcnt(2)" ::: "memory"); }         \
            else            { asm volatile("s_waitcnt vmcnt(0)" ::: "memory"); }         \
            __builtin_amdgcn_s_barrier();                                                \
        }                                                                                \
        s4v += 4; if (s4v >= 9) s4v -= 9;                                                \
    } }

    // epilogue: 32x32 C/D map col = lane&31, row = (r&3) + 8*(r>>2) + 4*(lane>>5)
#define EPI(BROWX) {                                                                     \
    _Pragma("unroll")                                                                    \
    for (int mf_ = 0; mf_ < 4; ++mf_) {                                                  \
        _Pragma("unroll")                                                                \
        for (int r_ = 0; r_ < 16; ++r_) {                                                \
            const int row_ = (BROWX) + wm * 128 + mf_ * 32                               \
                             + (r_ & 3) + 8 * (r_ >> 2) + 4 * kc32;                      \
            float* po_ = out + (size_t)row_ * OUT_F + ocol;                              \
            po_[0]  = acc[mf_][0][r_] + bsv0;                                            \
            po_[32] = acc[mf_][1][r_] + bsv1;                                            \
        } } }

    const int ocol = bcol + wn * 64 + l31;
    const float bsv0 = bias[ocol];
    const float bsv1 = bias[ocol + 32];

    // ---- row-tile g=0
    PRO(aSrc0);
    asm volatile("s_waitcnt vmcnt(2)" ::: "memory");
    __builtin_amdgcn_s_barrier();
    KLOOP(aSrc0);
    __builtin_amdgcn_s_barrier();            // slot safety: all g0 reads complete

    // ---- g=1 prologue; epilogue-0 stores drain under g1 compute
    PRO(aSrc1);
    asm volatile("s_waitcnt vmcnt(2)" ::: "memory");
    __builtin_amdgcn_s_barrier();
    EPI(brow0);
    #pragma unroll
    for (int a = 0; a < 4; ++a)
        #pragma unroll
        for (int n = 0; n < 2; ++n)
            #pragma unroll
            for (int e = 0; e < 16; ++e) acc[a][n][e] = 0.f;
    KLOOP(aSrc1);
    EPI(brow0 + 16 * BM);

#undef STG_UNIT
#undef GLOAD
#undef PRO
#undef KLOOP
#undef EPI
}

// ---- fallback (ws too small / odd M): fp32 tiled kernel, known correct
__global__ __launch_bounds__(256) void band_gemm_f32(
    const float* __restrict__ x, const float* __restrict__ wv,
    const float* __restrict__ bias, float* __restrict__ out, int M)
{
    __shared__ float Xs[128][33];
    __shared__ float Ws[32][130];
    const int tid = threadIdx.x;
    const int tx = tid & 15, ty = tid >> 4;
    const int bcol = blockIdx.x * 128, brow = blockIdx.y * 128;
    const int klo = (bcol >= BW) ? (bcol - BW) : 0;
    const int khi = min(IN_F, bcol + 128 + BW);
    float acc[8][8];
    #pragma unroll
    for (int a = 0; a < 8; ++a)
        #pragma unroll
        for (int b = 0; b < 8; ++b) acc[a][b] = 0.f;
    const int xc4 = (tid & 7) * 4, xr0 = tid >> 3;
    const int wc = tid & 31, wr0 = tid >> 5;
    for (int k0 = klo; k0 < khi; k0 += 32) {
        #pragma unroll
        for (int p = 0; p < 4; ++p) {
            const int rr = xr0 + 32 * p;
            const float4 v = *reinterpret_cast<const float4*>(&x[(size_t)(brow + rr) * IN_F + (k0 + xc4)]);
            Xs[rr][xc4 + 0] = v.x; Xs[rr][xc4 + 1] = v.y; Xs[rr][xc4 + 2] = v.z; Xs[rr][xc4 + 3] = v.w;
        }
        const int i = k0 + wc;
        #pragma unroll
        for (int p = 0; p < 16; ++p) {
            const int rr = wr0 + 8 * p;
            const int o = bcol + rr;
            const int lo = (o >= BW) ? (o - BW) : 0;
            float v = 0.f;
            if (i >= o - BW && i <= o + BW) v = wv[band_start(o) + (i - lo)];
            Ws[wc][rr] = v;
        }
        __syncthreads();
        #pragma unroll
        for (int k = 0; k < 32; ++k) {
            float amv[8];
            #pragma unroll
            for (int a = 0; a < 8; ++a) amv[a] = Xs[ty * 8 + a][k];
            float bo[8];
            #pragma unroll
            for (int b = 0; b < 4; ++b) { bo[b] = Ws[k][tx * 4 + b]; bo[4 + b] = Ws[k][tx * 4 + 64 + b]; }
            #pragma unroll
            for (int a = 0; a < 8; ++a)
                #pragma unroll
                for (int b = 0; b < 8; ++b) acc[a][b] = fmaf(amv[a], bo[b], acc[a][b]);
        }
        __syncthreads();
    }
    #pragma unroll
    for (int a = 0; a < 8; ++a) {
        const size_t row = (size_t)(brow + ty * 8 + a);
        #pragma unroll
        for (int b = 0; b < 4; ++b) {
            out[row * OUT_F + bcol + tx * 4 + b]      = acc[a][b]     + bias[bcol + tx * 4 + b];
            out[row * OUT_F + bcol + tx * 4 + 64 + b] = acc[a][4 + b] + bias[bcol + tx * 4 + 64 + b];
        }
    }
}

extern "C" void kernel_launch(void* const* d_in, const int* in_sizes, int n_in,
                              void* d_out, int out_size, void* d_ws, size_t ws_size,
                              hipStream_t stream) {
    const float* x    = (const float*)d_in[0];
    const float* wv   = (const float*)d_in[1];
    const float* bias = (const float*)d_in[2];
    float* out        = (float*)d_out;

    const int M = in_sizes[0] / IN_F;                         // 8192
    const size_t xb_bytes = (size_t)M * IN_F * 2;             // 64 MB
    const size_t wd_bytes = (size_t)OUT_F * WB2 * 2;          // 10.5 MB

    if (ws_size >= xb_bytes + wd_bytes && M == 8192) {
        uint16_t* xb  = (uint16_t*)d_ws;
        uint16_t* wdp = (uint16_t*)((uint8_t*)d_ws + xb_bytes);
        cvt_x<<<2048, 256, 0, stream>>>(x, xb, M * IN_F / 4);
        cvt_w<<<dim3(WB2 / 256, OUT_F), 256, 0, stream>>>(wv, wdp);
        band_gemm_v12<<<256, 512, 0, stream>>>(xb, wdp, bias, out);
    } else {
        dim3 grid(OUT_F / 128, M / 128);
        band_gemm_f32<<<grid, 256, 0, stream>>>(x, wv, bias, out, M);
    }
}